// Round 11
// baseline (148.941 us; speedup 1.0000x reference)
//
#include <hip/hip_runtime.h>
#include <hip/hip_fp16.h>
#include <math.h>

#define FL     8192
#define BS     4096      // block step = FL/2
#define CD     16
#define BATCH  32
#define SEQ    262144
#define NPAIR  32        // 64 blocks -> 32 pairs
#define LDSN   8448      // 8192 + 256 pad (one per 32)

// Packed fp32 complex: <2 x float> -> v_pk_add_f32 / v_pk_fma_f32 on gfx950.
typedef float vf2 __attribute__((ext_vector_type(2)));
__device__ __forceinline__ vf2 mkv(float x, float y){ vf2 v; v.x = x; v.y = y; return v; }
__device__ __forceinline__ vf2 cmul(vf2 a, vf2 b){            // a * b
    const vf2 c = mkv(-a.y, a.x) * mkv(b.y, b.y);
    return a * mkv(b.x, b.x) + c;
}
__device__ __forceinline__ vf2 cmulc(vf2 a, vf2 b){           // a * conj(b)
    const vf2 c = mkv(a.y, -a.x) * mkv(b.y, b.y);
    return a * mkv(b.x, b.x) + c;
}
__device__ __forceinline__ vf2 mri(vf2 a, float c, float s){  // a * (c + i s)
    const vf2 t = mkv(-a.y, a.x) * mkv(s, s);
    return a * mkv(c, c) + t;
}

// fp16 LDS staging (addresses are PRE-PADDED by caller)
__device__ __forceinline__ void sth(__half2* buf, int i, vf2 v){ buf[i] = __floats2half2_rn(v.x, v.y); }
__device__ __forceinline__ vf2 ldh(const __half2* buf, int i){ const float2 f = __half22float2(buf[i]); return mkv(f.x, f.y); }
// fp32 twiddle table read
__device__ __forceinline__ vf2 ldT(const float2* __restrict__ T, int k){ const float2 v = T[k]; return mkv(v.x, v.y); }

// Digit-reversed bin stored at position p after DIF passes
// A(R16,s512), B(R16,s32), C(R2,s16), D(R16,s1):
// k = qA + 16*qB + 256*qC + 512*qD ; p = 512*qA + 32*qB + 16*qC + qD
__device__ __forceinline__ int bin_of_pos(int p){
    return ((p>>9)&15) | (((p>>5)&15)<<4) | (((p>>4)&1)<<8) | ((p&15)<<9);
}

// ---------------------------------------------------------------------------
// Master twiddle table: T[k] = e^{-2*pi*i*k/FL}, k in [0, FL)
// ---------------------------------------------------------------------------
__global__ void tw_kernel(float2* __restrict__ T){
    const int k = blockIdx.x*256 + threadIdx.x;
    if (k < FL){
        const double a = -2.0 * M_PI * (double)k / (double)FL;
        T[k] = make_float2((float)cos(a), (float)sin(a));
    }
}

// ---------------------------------------------------------------------------
// In-register 16-point DFT, natural order in/out, 4x4 Cooley-Tukey.
// INV: conjugate (inverse, unnormalized). HALF: inputs d[8..15] are zero.
// ---------------------------------------------------------------------------
template<bool INV, bool HALF>
__device__ __forceinline__ void dft16(vf2* d){
    constexpr float sgn = INV ? 1.f : -1.f;          // e^{sgn*i*2pi*k/16}
    constexpr float C1 = 0.923879532511287f;          // cos(pi/8)
    constexpr float S1 = 0.382683432365090f;          // sin(pi/8)
    constexpr float R  = 0.707106781186548f;
    vf2 u[16];
#pragma unroll
    for (int b=0;b<4;++b){
        const vf2 a0=d[b], a1=d[4+b];
        if (HALF){
            const vf2 ja1 = mkv(-sgn*a1.y, sgn*a1.x);
            u[4*b+0]=a0+a1;
            u[4*b+1]=a0+ja1;
            u[4*b+2]=a0-a1;
            u[4*b+3]=a0-ja1;
        } else {
            const vf2 a2=d[8+b], a3=d[12+b];
            const vf2 s0=a0+a2, s1=a0-a2;
            const vf2 s2=a1+a3, s3=a1-a3;
            const vf2 js3 = mkv(-sgn*s3.y, sgn*s3.x);
            u[4*b+0]=s0+s2;
            u[4*b+1]=s1+js3;
            u[4*b+2]=s0-s2;
            u[4*b+3]=s1-js3;
        }
    }
    u[4+1] = mri(u[4+1],  C1, sgn*S1);
    u[4+2] = mri(u[4+2],  R,  sgn*R );
    u[4+3] = mri(u[4+3],  S1, sgn*C1);
    u[8+1] = mri(u[8+1],  R,  sgn*R );
    u[8+2] = mri(u[8+2],  0.f, sgn);
    u[8+3] = mri(u[8+3], -R,  sgn*R );
    u[12+1]= mri(u[12+1], S1, sgn*C1);
    u[12+2]= mri(u[12+2],-R,  sgn*R );
    u[12+3]= mri(u[12+3],-C1,-sgn*S1);
#pragma unroll
    for (int c=0;c<4;++c){
        const vf2 a0=u[c], a1=u[4+c], a2=u[8+c], a3=u[12+c];
        const vf2 s0=a0+a2, s1=a0-a2;
        const vf2 s2=a1+a3, s3=a1-a3;
        const vf2 js3 = mkv(-sgn*s3.y, sgn*s3.x);
        d[c+0] =s0+s2;
        d[c+4] =s1+js3;
        d[c+8] =s0-s2;
        d[c+12]=s1-js3;
    }
}

// ---------------------------------------------------------------------------
// Heff per (batch, position): Heff[f] = (H[f] + conj(H[(N-f)%N]))/2 / N,
// stored at digit-reversed position p (natural/unpadded global array).
// ---------------------------------------------------------------------------
__global__ void h_kernel(const float* __restrict__ c,  const float* __restrict__ Wf,
                         const float* __restrict__ bfv, const float* __restrict__ Wp,
                         const float* __restrict__ bpv, float2* __restrict__ H){
    const int p = blockIdx.x*256 + threadIdx.x;
    const int b = blockIdx.y;
    const int f = bin_of_pos(p);
    const int g = (FL - f) & (FL - 1);
    float amf = bfv[f], apf = bpv[f], amg = bfv[g], apg = bpv[g];
#pragma unroll
    for (int i=0;i<CD;++i){
        const float cv = c[b*CD + i];
        amf += cv * Wf[f*CD + i];
        apf += cv * Wp[f*CD + i];
        amg += cv * Wf[g*CD + i];
        apg += cv * Wp[g*CD + i];
    }
    const float magf = 1.f/(1.f+__expf(-amf));
    const float magg = 1.f/(1.f+__expf(-amg));
    float sf, cf2, sg, cg2;
    __sincosf(apf, &sf, &cf2);
    __sincosf(apg, &sg, &cg2);
    const float scale = 0.5f / (float)FL;
    H[(size_t)b*FL + p] = make_float2((magf*cf2 + magg*cg2)*scale,
                                      (magf*sf  - magg*sg )*scale);
}

// ---------------------------------------------------------------------------
// One WG (512 thr) per (block-pair, batch). Register-resident mixed-radix FFT,
// fp16 LDS staging, pad-per-32 addressing (ds offsets fold to immediates).
// All twiddles from the global fp32 table T (L2-resident, 64 KB): no sincos,
// no chain cmuls, no serial dependencies. Inverse passes use cmulc (conj).
// Output written DIRECTLY from A' registers: y[j+512m] is lane-contiguous for
// fixed m (r7's park/out round-trip was a misdiagnosis; r5 pattern restored).
// __launch_bounds__(512,4): r5/r8/r9-proven no-spill region.
// ---------------------------------------------------------------------------
__global__ __launch_bounds__(512, 4) void fft_kernel(const float*  __restrict__ x,
                                                     const float2* __restrict__ H,
                                                     const float2* __restrict__ T,
                                                     float* __restrict__ out){
    extern __shared__ __half2 buf[];     // 8448 * 4B = 33 KiB
    const int t  = threadIdx.x;
    const int pr = blockIdx.x;
    const int b  = blockIdx.y;
    const float* xb = x + (size_t)b*SEQ;
    const int s0 = 2*pr*BS - (FL-1);

    vf2 d[16];

    constexpr float CT[16] = { 1.f, 0.980785280403230f, 0.923879532511287f, 0.831469612302545f,
                               0.707106781186548f, 0.555570233019602f, 0.382683432365090f, 0.195090322016128f,
                               0.f,-0.195090322016128f,-0.382683432365090f,-0.555570233019602f,
                              -0.707106781186548f,-0.831469612302545f,-0.923879532511287f,-0.980785280403230f };
    constexpr float ST[16] = { 0.f, 0.195090322016128f, 0.382683432365090f, 0.555570233019602f,
                               0.707106781186548f, 0.831469612302545f, 0.923879532511287f, 0.980785280403230f,
                               1.f, 0.980785280403230f, 0.923879532511287f, 0.831469612302545f,
                               0.707106781186548f, 0.555570233019602f, 0.382683432365090f, 0.195090322016128f };

    // ---- Pass A: radix-16, stride 512 (input half-zero) ----
    {
        const int j = t;
        if (pr == 0){
#pragma unroll
            for (int m=0;m<8;++m){
                const int k  = j + 512*m;
                const int ua = s0 + k, ub = ua + BS;
                const float va = (ua >= 0) ? xb[ua] : 0.f;
                const float vb = (ub >= 0) ? xb[ub] : 0.f;
                d[m] = mkv(va, vb);
            }
        } else {
            const float* bp = xb + s0;
#pragma unroll
            for (int m=0;m<8;++m){
                const int k = j + 512*m;
                d[m] = mkv(bp[k], bp[k + BS]);
            }
        }
        dft16<false,true>(d);
#pragma unroll
        for (int q=1;q<16;++q) d[q] = cmul(d[q], ldT(T, j*q));
        const int a0 = j + (j>>5);             // PA(j); offsets 528*q constant
#pragma unroll
        for (int q=0;q<16;++q) sth(buf, a0 + 528*q, d[q]);
    }
    __syncthreads();

    // ---- Pass B: radix-16, stride 32 ----
    {
        const int base = ((t>>5)<<9) + (t&31);
        const int j = t&31;
        const int a0 = base + (base>>5);       // PA(base); offsets 33*m constant
#pragma unroll
        for (int m=0;m<16;++m) d[m] = ldh(buf, a0 + 33*m);
        dft16<false,false>(d);
#pragma unroll
        for (int q=1;q<16;++q) d[q] = cmul(d[q], ldT(T, (j<<4)*q));
#pragma unroll
        for (int q=0;q<16;++q) sth(buf, a0 + 33*q, d[q]);
    }
    __syncthreads();

    // ---- Pass C: radix-2, stride 16, tw W_32^j on odd output ----
    {
        const int r = t&1, base = 32*(t>>1) + 8*r;
        const int a0 = base + (t>>1);          // PA(base); (8r+jj(+16)) < 32, no carry
#pragma unroll
        for (int jj=0;jj<8;++jj){
            const vf2 a  = ldh(buf, a0 + jj);
            const vf2 bb = ldh(buf, a0 + jj + 16);
            const float ck = r ? CT[jj+8] : CT[jj];
            const float sk = r ? ST[jj+8] : ST[jj];
            sth(buf, a0 + jj,      a + bb);
            sth(buf, a0 + jj + 16, mri(a - bb, ck, -sk));
        }
    }
    __syncthreads();

    // ---- Pass D: DFT16 x Heff x IDFT16, contiguous 16-block ----
    {
        const int a0 = (t<<4) + (t>>1);        // PA(16t); offsets i < 16
#pragma unroll
        for (int i=0;i<16;++i) d[i] = ldh(buf, a0 + i);
        dft16<false,false>(d);
        const float4* H4 = reinterpret_cast<const float4*>(H + (size_t)b*FL + (t<<4));
#pragma unroll
        for (int q=0;q<8;++q){
            const float4 hv = H4[q];
            d[2*q]   = cmul(d[2*q],   mkv(hv.x, hv.y));
            d[2*q+1] = cmul(d[2*q+1], mkv(hv.z, hv.w));
        }
        dft16<true,false>(d);
#pragma unroll
        for (int i=0;i<16;++i) sth(buf, a0 + i, d[i]);
    }
    __syncthreads();

    // ---- Pass C': inverse radix-2, stride 16, conj tw before butterfly ----
    {
        const int r = t&1, base = 32*(t>>1) + 8*r;
        const int a0 = base + (t>>1);
#pragma unroll
        for (int jj=0;jj<8;++jj){
            const vf2 a  = ldh(buf, a0 + jj);
            const vf2 bb = ldh(buf, a0 + jj + 16);
            const float ck = r ? CT[jj+8] : CT[jj];
            const float sk = r ? ST[jj+8] : ST[jj];
            const vf2 tb = mri(bb, ck, sk);
            sth(buf, a0 + jj,      a + tb);
            sth(buf, a0 + jj + 16, a - tb);
        }
    }
    __syncthreads();

    // ---- Pass B': inverse radix-16, stride 32 (conj table twiddles) ----
    {
        const int base = ((t>>5)<<9) + (t&31);
        const int j = t&31;
        const int a0 = base + (base>>5);
        d[0] = ldh(buf, a0);
#pragma unroll
        for (int q=1;q<16;++q) d[q] = cmulc(ldh(buf, a0 + 33*q), ldT(T, (j<<4)*q));
        dft16<true,false>(d);
#pragma unroll
        for (int m=0;m<16;++m) sth(buf, a0 + 33*m, d[m]);
    }
    __syncthreads();

    // ---- Pass A': inverse radix-16, stride 512; direct overlap-add ----
    {
        const int j = t;
        const int a0 = j + (j>>5);
        d[0] = ldh(buf, a0);
#pragma unroll
        for (int q=1;q<16;++q) d[q] = cmulc(ldh(buf, a0 + 528*q), ldT(T, j*q));
        dft16<true,false>(d);
        // d[m] = y[time j + 512*m]; Re -> block a, Im -> block b.
        // For fixed m, lanes j are 4B-contiguous: coalesced.
        float* ob = out + (size_t)b*SEQ;
        const int pa = 2*pr*BS;
        const bool last = (pr == NPAIR-1);
#pragma unroll
        for (int mm=0;mm<8;++mm){
            const int klo = j + 512*mm;                      // 0..4095
            atomicAdd(&ob[pa+klo], d[mm].x);                 // even span (2 writers)
            ob[pa+BS+klo] = d[mm+8].x + d[mm].y;             // odd span (sole writer)
            if (!last) atomicAdd(&ob[pa+2*BS+klo], d[mm+8].y); // even span (2 writers)
        }
    }
}

// ---------------------------------------------------------------------------
extern "C" void kernel_launch(void* const* d_in, const int* in_sizes, int n_in,
                              void* d_out, int out_size, void* d_ws, size_t ws_size,
                              hipStream_t stream) {
    const float* x   = (const float*)d_in[0];
    const float* c   = (const float*)d_in[1];
    const float* Wf  = (const float*)d_in[2];
    const float* bfv = (const float*)d_in[3];
    const float* Wp  = (const float*)d_in[4];
    const float* bpv = (const float*)d_in[5];

    float*  out = (float*)d_out;
    float2* H   = (float2*)d_ws;                                  // 2 MiB
    float2* T   = (float2*)((char*)d_ws + (size_t)BATCH*FL*sizeof(float2)); // 64 KiB

    hipMemsetAsync(d_out, 0, (size_t)out_size*sizeof(float), stream);
    tw_kernel<<<FL/256, 256, 0, stream>>>(T);
    h_kernel<<<dim3(FL/256, BATCH), 256, 0, stream>>>(c, Wf, bfv, Wp, bpv, H);
    fft_kernel<<<dim3(NPAIR, BATCH), 512, LDSN*sizeof(__half2), stream>>>(x, H, T, out);
}

// Round 12
// 72.223 us; speedup vs baseline: 2.0622x; 2.0622x over previous
//
#include <hip/hip_runtime.h>
#include <hip/hip_fp16.h>
#include <math.h>

#define FL     8192
#define BS     4096      // block step = FL/2
#define CD     16
#define BATCH  32
#define SEQ    262144
#define NPAIR  32        // 64 blocks -> 32 pairs
#define LDSN   8448      // 256 blocks * 33 (32 + 1 pad)

// Packed fp32 complex: <2 x float> -> v_pk_add_f32 / v_pk_fma_f32 on gfx950.
typedef float vf2 __attribute__((ext_vector_type(2)));
__device__ __forceinline__ vf2 mkv(float x, float y){ vf2 v; v.x = x; v.y = y; return v; }
__device__ __forceinline__ vf2 cmul(vf2 a, vf2 b){            // a * b
    const vf2 c = mkv(-a.y, a.x) * mkv(b.y, b.y);
    return a * mkv(b.x, b.x) + c;
}
__device__ __forceinline__ vf2 mri(vf2 a, float c, float s){  // a * (c + i s)
    const vf2 t = mkv(-a.y, a.x) * mkv(s, s);
    return a * mkv(c, c) + t;
}

// fp16 LDS staging (addresses are PRE-PADDED by caller)
__device__ __forceinline__ void sth(__half2* buf, int i, vf2 v){ buf[i] = __floats2half2_rn(v.x, v.y); }
__device__ __forceinline__ vf2 ldh(const __half2* buf, int i){ const float2 f = __half22float2(buf[i]); return mkv(f.x, f.y); }

// Digit-reversed bin stored at flat position p after passes
// A(R16,s512), B(R16,s32), E(DFT32 natural within contiguous 32-block):
// p = 512*qA + 32*qB + w  ->  k = qA + 16*qB + 256*w
__device__ __forceinline__ int bin_of_pos(int p){
    return ((p>>9)&15) | (((p>>5)&15)<<4) | ((p&31)<<8);
}

// ---------------------------------------------------------------------------
// In-register 16-point DFT over d[S*0..S*15], 4x4 Cooley-Tukey.
// INV: conjugate (inverse, unnormalized). HALF: inputs d[S*8..S*15] are zero.
// ---------------------------------------------------------------------------
template<bool INV, bool HALF, int S>
__device__ __forceinline__ void dft16(vf2* d){
    constexpr float sgn = INV ? 1.f : -1.f;          // e^{sgn*i*2pi*k/16}
    constexpr float C1 = 0.923879532511287f;          // cos(pi/8)
    constexpr float S1 = 0.382683432365090f;          // sin(pi/8)
    constexpr float R  = 0.707106781186548f;
    vf2 u[16];
#pragma unroll
    for (int b=0;b<4;++b){
        const vf2 a0=d[S*b], a1=d[S*(4+b)];
        if (HALF){
            const vf2 ja1 = mkv(-sgn*a1.y, sgn*a1.x);
            u[4*b+0]=a0+a1;
            u[4*b+1]=a0+ja1;
            u[4*b+2]=a0-a1;
            u[4*b+3]=a0-ja1;
        } else {
            const vf2 a2=d[S*(8+b)], a3=d[S*(12+b)];
            const vf2 s0=a0+a2, s1=a0-a2;
            const vf2 s2=a1+a3, s3=a1-a3;
            const vf2 js3 = mkv(-sgn*s3.y, sgn*s3.x);
            u[4*b+0]=s0+s2;
            u[4*b+1]=s1+js3;
            u[4*b+2]=s0-s2;
            u[4*b+3]=s1-js3;
        }
    }
    u[4+1] = mri(u[4+1],  C1, sgn*S1);
    u[4+2] = mri(u[4+2],  R,  sgn*R );
    u[4+3] = mri(u[4+3],  S1, sgn*C1);
    u[8+1] = mri(u[8+1],  R,  sgn*R );
    u[8+2] = mri(u[8+2],  0.f, sgn);
    u[8+3] = mri(u[8+3], -R,  sgn*R );
    u[12+1]= mri(u[12+1], S1, sgn*C1);
    u[12+2]= mri(u[12+2],-R,  sgn*R );
    u[12+3]= mri(u[12+3],-C1,-sgn*S1);
#pragma unroll
    for (int c=0;c<4;++c){
        const vf2 a0=u[c], a1=u[4+c], a2=u[8+c], a3=u[12+c];
        const vf2 s0=a0+a2, s1=a0-a2;
        const vf2 s2=a1+a3, s3=a1-a3;
        const vf2 js3 = mkv(-sgn*s3.y, sgn*s3.x);
        d[S*(c+0)] =s0+s2;
        d[S*(c+4)] =s1+js3;
        d[S*(c+8)] =s0-s2;
        d[S*(c+12)]=s1-js3;
    }
}

// chained twiddle: d[q] *= w1^q, q=1..15 (w1 = e^{±i theta}; conj handled by caller's angle sign)
__device__ __forceinline__ void twiddle_chain(vf2* d, vf2 w1){
    vf2 wq = w1;
    d[1] = cmul(d[1], wq);
#pragma unroll
    for (int q=2;q<16;++q){ wq = cmul(wq, w1); d[q] = cmul(d[q], wq); }
}
// same w1^q applied to d[q] and d[16+q] (shared-twiddle butterfly pair)
__device__ __forceinline__ void twiddle_chain2(vf2* d, vf2 w1){
    vf2 wq = w1;
    d[1] = cmul(d[1], wq); d[17] = cmul(d[17], wq);
#pragma unroll
    for (int q=2;q<16;++q){ wq = cmul(wq, w1); d[q] = cmul(d[q], wq); d[16+q] = cmul(d[16+q], wq); }
}

// ---------------------------------------------------------------------------
// Heff per (batch, position): Heff[f] = (H[f] + conj(H[(N-f)%N]))/2 / N,
// stored at digit-reversed position p (natural/unpadded global array).
// ---------------------------------------------------------------------------
__global__ void h_kernel(const float* __restrict__ c,  const float* __restrict__ Wf,
                         const float* __restrict__ bfv, const float* __restrict__ Wp,
                         const float* __restrict__ bpv, float2* __restrict__ H){
    const int p = blockIdx.x*256 + threadIdx.x;
    const int b = blockIdx.y;
    const int f = bin_of_pos(p);
    const int g = (FL - f) & (FL - 1);
    float amf = bfv[f], apf = bpv[f], amg = bfv[g], apg = bpv[g];
#pragma unroll
    for (int i=0;i<CD;++i){
        const float cv = c[b*CD + i];
        amf += cv * Wf[f*CD + i];
        apf += cv * Wp[f*CD + i];
        amg += cv * Wf[g*CD + i];
        apg += cv * Wp[g*CD + i];
    }
    const float magf = 1.f/(1.f+__expf(-amf));
    const float magg = 1.f/(1.f+__expf(-amg));
    float sf, cf2, sg, cg2;
    __sincosf(apf, &sf, &cf2);
    __sincosf(apg, &sg, &cg2);
    const float scale = 0.5f / (float)FL;
    H[(size_t)b*FL + p] = make_float2((magf*cf2 + magg*cg2)*scale,
                                      (magf*sf  - magg*sg )*scale);
}

// ---------------------------------------------------------------------------
// One WG (256 thr x 32 elements) per (block-pair, batch).
// A : global->reg, 2x DFT16(half, j=t & t+256), tw W_8192^{jq}, ->LDS (s512)
// B : 2x DFT16 (groups g,g+8; SHARED twiddle W_512^{j2 q})          (s32)
// E : contiguous 32-block: DFT32 (even/odd DIT, const W32) x Heff x IDFT32
// B', A': mirrors with positive-angle twiddles.
// LDS layout: block stride 33 (addr = 33*(e>>5) + (e&31)); all passes 2-way.
// launch_bounds(256,3): ~170 VGPR budget -- avoids the 64-cap spill trap
// ((512,4) pinned r5/r8/r11 at exactly 64 and spilled r11).
// ---------------------------------------------------------------------------
__global__ __launch_bounds__(256, 3) void fft_kernel(const float*  __restrict__ x,
                                                     const float2* __restrict__ H,
                                                     float* __restrict__ out){
    extern __shared__ __half2 buf[];     // 8448 * 4B = 33 KiB
    const int t  = threadIdx.x;          // 0..255
    const int pr = blockIdx.x;
    const int b  = blockIdx.y;
    const float* xb = x + (size_t)b*SEQ;
    const int s0 = 2*pr*BS - (FL-1);
    const float TWO_PI = 6.28318530717958647692f;

    vf2 d[32];

    constexpr float CT[16] = { 1.f, 0.980785280403230f, 0.923879532511287f, 0.831469612302545f,
                               0.707106781186548f, 0.555570233019602f, 0.382683432365090f, 0.195090322016128f,
                               0.f,-0.195090322016128f,-0.382683432365090f,-0.555570233019602f,
                              -0.707106781186548f,-0.831469612302545f,-0.923879532511287f,-0.980785280403230f };
    constexpr float ST[16] = { 0.f, 0.195090322016128f, 0.382683432365090f, 0.555570233019602f,
                               0.707106781186548f, 0.831469612302545f, 0.923879532511287f, 0.980785280403230f,
                               1.f, 0.980785280403230f, 0.923879532511287f, 0.831469612302545f,
                               0.707106781186548f, 0.555570233019602f, 0.382683432365090f, 0.195090322016128f };

    const int pa0 = t + (t>>5);          // padded addr of j=t      (j + j>>5)
    // padded addr of j=t+256 is pa0 + 264  (256 + 8 pad)

    // ---- Pass A: radix-16, stride 512; butterflies j=t and j=t+256 ----
    {
        if (pr == 0){
#pragma unroll
            for (int h=0; h<2; ++h){
                const int j = t + 256*h;
#pragma unroll
                for (int m=0;m<8;++m){
                    const int k  = j + 512*m;
                    const int ua = s0 + k, ub = ua + BS;
                    const float va = (ua >= 0) ? xb[ua] : 0.f;
                    const float vb = (ub >= 0) ? xb[ub] : 0.f;
                    d[16*h + m] = mkv(va, vb);
                }
            }
        } else {
            const float* bp = xb + s0;
#pragma unroll
            for (int h=0; h<2; ++h){
                const int j = t + 256*h;
#pragma unroll
                for (int m=0;m<8;++m){
                    const int k = j + 512*m;
                    d[16*h + m] = mkv(bp[k], bp[k + BS]);
                }
            }
        }
        dft16<false,true,1>(d);
        dft16<false,true,1>(d+16);
        float sn0, cs0, sn1, cs1;
        __sincosf(-TWO_PI * (float)t        / 8192.f, &sn0, &cs0);
        __sincosf(-TWO_PI * (float)(t+256)  / 8192.f, &sn1, &cs1);
        twiddle_chain(d,    mkv(cs0, sn0));
        twiddle_chain(d+16, mkv(cs1, sn1));
#pragma unroll
        for (int q=0;q<16;++q){
            sth(buf, pa0       + 528*q, d[q]);
            sth(buf, pa0 + 264 + 528*q, d[16+q]);
        }
    }
    __syncthreads();

    // ---- Pass B: radix-16, stride 32; groups g=t>>5 and g+8, shared j2 ----
    {
        const int j2 = t & 31;
        const int a0 = 528*(t>>5) + j2;    // group g
        const int a1 = a0 + 4224;          // group g+8 (528*8)
#pragma unroll
        for (int m=0;m<16;++m){
            d[m]    = ldh(buf, a0 + 33*m);
            d[16+m] = ldh(buf, a1 + 33*m);
        }
        dft16<false,false,1>(d);
        dft16<false,false,1>(d+16);
        float sn, cs; __sincosf(-TWO_PI * (float)j2 / 512.f, &sn, &cs);
        twiddle_chain2(d, mkv(cs, sn));
#pragma unroll
        for (int q=0;q<16;++q){
            sth(buf, a0 + 33*q, d[q]);
            sth(buf, a1 + 33*q, d[16+q]);
        }
    }
    __syncthreads();

    // ---- Pass E: contiguous 32-block t: DFT32 x Heff x IDFT32 ----
    {
        const int a0 = 33*t;
#pragma unroll
        for (int i=0;i<32;++i) d[i] = ldh(buf, a0 + i);
        dft16<false,false,2>(d);       // even elems -> E[k] at d[2k]
        dft16<false,false,2>(d+1);     // odd  elems -> O[k] at d[2k+1]
        const float2* Hb = H + (size_t)b*FL + (t<<5);
#pragma unroll
        for (int w=0;w<16;++w){
            const vf2 Ow = mri(d[2*w+1], CT[w], -ST[w]);   // W32^w * O[w]
            const vf2 Ew = d[2*w];
            vf2 Xlo = Ew + Ow;                             // bin w
            vf2 Xhi = Ew - Ow;                             // bin w+16
            const float2 h0 = Hb[w], h1 = Hb[w+16];
            Xlo = cmul(Xlo, mkv(h0.x, h0.y));
            Xhi = cmul(Xhi, mkv(h1.x, h1.y));
            d[2*w]   = Xlo + Xhi;                          // A_w
            d[2*w+1] = mri(Xlo - Xhi, CT[w], ST[w]);       // B_w = (Xlo-Xhi)*conj(W32^w)
        }
        dft16<true,false,2>(d);        // y[2i]   at d[2i]
        dft16<true,false,2>(d+1);      // y[2i+1] at d[2i+1]
#pragma unroll
        for (int i=0;i<32;++i) sth(buf, a0 + i, d[i]);
    }
    __syncthreads();

    // ---- Pass B': inverse radix-16, stride 32 (positive-angle twiddles) ----
    {
        const int j2 = t & 31;
        const int a0 = 528*(t>>5) + j2;
        const int a1 = a0 + 4224;
#pragma unroll
        for (int q=0;q<16;++q){
            d[q]    = ldh(buf, a0 + 33*q);
            d[16+q] = ldh(buf, a1 + 33*q);
        }
        float sn, cs; __sincosf(TWO_PI * (float)j2 / 512.f, &sn, &cs);
        twiddle_chain2(d, mkv(cs, sn));
        dft16<true,false,1>(d);
        dft16<true,false,1>(d+16);
#pragma unroll
        for (int m=0;m<16;++m){
            sth(buf, a0 + 33*m, d[m]);
            sth(buf, a1 + 33*m, d[16+m]);
        }
    }
    __syncthreads();

    // ---- Pass A': inverse radix-16, stride 512; direct overlap-add ----
    {
#pragma unroll
        for (int q=0;q<16;++q){
            d[q]    = ldh(buf, pa0       + 528*q);
            d[16+q] = ldh(buf, pa0 + 264 + 528*q);
        }
        float sn0, cs0, sn1, cs1;
        __sincosf(TWO_PI * (float)t       / 8192.f, &sn0, &cs0);
        __sincosf(TWO_PI * (float)(t+256) / 8192.f, &sn1, &cs1);
        twiddle_chain(d,    mkv(cs0, sn0));
        twiddle_chain(d+16, mkv(cs1, sn1));
        dft16<true,false,1>(d);
        dft16<true,false,1>(d+16);
        // d[16h+m] = y[time (t+256h) + 512m]; Re -> block a, Im -> block b.
        float* ob = out + (size_t)b*SEQ;
        const int pa = 2*pr*BS;
        const bool last = (pr == NPAIR-1);
#pragma unroll
        for (int h=0; h<2; ++h){
            const int j = t + 256*h;
#pragma unroll
            for (int mm=0;mm<8;++mm){
                const int klo = j + 512*mm;                      // 0..4095
                const vf2 ylo = d[16*h + mm];
                const vf2 yhi = d[16*h + mm + 8];
                atomicAdd(&ob[pa+klo], ylo.x);                   // even span (2 writers)
                ob[pa+BS+klo] = yhi.x + ylo.y;                   // odd span (sole writer)
                if (!last) atomicAdd(&ob[pa+2*BS+klo], yhi.y);   // even span (2 writers)
            }
        }
    }
}

// ---------------------------------------------------------------------------
extern "C" void kernel_launch(void* const* d_in, const int* in_sizes, int n_in,
                              void* d_out, int out_size, void* d_ws, size_t ws_size,
                              hipStream_t stream) {
    const float* x   = (const float*)d_in[0];
    const float* c   = (const float*)d_in[1];
    const float* Wf  = (const float*)d_in[2];
    const float* bfv = (const float*)d_in[3];
    const float* Wp  = (const float*)d_in[4];
    const float* bpv = (const float*)d_in[5];

    float*  out = (float*)d_out;
    float2* H   = (float2*)d_ws;                      // BATCH*FL*8B = 2 MiB

    hipMemsetAsync(d_out, 0, (size_t)out_size*sizeof(float), stream);
    h_kernel<<<dim3(FL/256, BATCH), 256, 0, stream>>>(c, Wf, bfv, Wp, bpv, H);
    fft_kernel<<<dim3(NPAIR, BATCH), 256, LDSN*sizeof(__half2), stream>>>(x, H, out);
}

// Round 13
// 62.142 us; speedup vs baseline: 2.3968x; 1.1622x over previous
//
#include <hip/hip_runtime.h>
#include <hip/hip_fp16.h>
#include <math.h>

#define FL     8192
#define BS     4096      // block step = FL/2
#define CD     16
#define BATCH  32
#define SEQ    262144
#define NPAIR  32        // 64 blocks -> 32 pairs
#define LDSN   8448      // 256 blocks * 33 (32 + 1 pad)

// Packed fp32 complex: <2 x float> -> v_pk_add_f32 / v_pk_fma_f32 on gfx950.
typedef float vf2 __attribute__((ext_vector_type(2)));
__device__ __forceinline__ vf2 mkv(float x, float y){ vf2 v; v.x = x; v.y = y; return v; }
__device__ __forceinline__ vf2 cmul(vf2 a, vf2 b){            // a * b
    const vf2 c = mkv(-a.y, a.x) * mkv(b.y, b.y);
    return a * mkv(b.x, b.x) + c;
}
__device__ __forceinline__ vf2 mri(vf2 a, float c, float s){  // a * (c + i s)
    const vf2 t = mkv(-a.y, a.x) * mkv(s, s);
    return a * mkv(c, c) + t;
}

// fp16 LDS staging (addresses are PRE-PADDED by caller)
__device__ __forceinline__ void sth(__half2* buf, int i, vf2 v){ buf[i] = __floats2half2_rn(v.x, v.y); }
__device__ __forceinline__ vf2 ldh(const __half2* buf, int i){ const float2 f = __half22float2(buf[i]); return mkv(f.x, f.y); }

// flat position p <-> natural bin k maps for passes A(R16,s512),B(R16,s32),E(32-block)
// p = 512*qA + 32*qB + w  <->  k = qA + 16*qB + 256*w
__device__ __forceinline__ int pos_of_bin(int k){
    return ((k&15)<<9) | (((k>>4)&15)<<5) | (k>>8);
}

// ---------------------------------------------------------------------------
// In-register 16-point DFT over d[S*0..S*15], 4x4 Cooley-Tukey.
// INV: conjugate (inverse, unnormalized). HALF: inputs d[S*8..S*15] are zero.
// ---------------------------------------------------------------------------
template<bool INV, bool HALF, int S>
__device__ __forceinline__ void dft16(vf2* d){
    constexpr float sgn = INV ? 1.f : -1.f;          // e^{sgn*i*2pi*k/16}
    constexpr float C1 = 0.923879532511287f;          // cos(pi/8)
    constexpr float S1 = 0.382683432365090f;          // sin(pi/8)
    constexpr float R  = 0.707106781186548f;
    vf2 u[16];
#pragma unroll
    for (int b=0;b<4;++b){
        const vf2 a0=d[S*b], a1=d[S*(4+b)];
        if (HALF){
            const vf2 ja1 = mkv(-sgn*a1.y, sgn*a1.x);
            u[4*b+0]=a0+a1;
            u[4*b+1]=a0+ja1;
            u[4*b+2]=a0-a1;
            u[4*b+3]=a0-ja1;
        } else {
            const vf2 a2=d[S*(8+b)], a3=d[S*(12+b)];
            const vf2 s0=a0+a2, s1=a0-a2;
            const vf2 s2=a1+a3, s3=a1-a3;
            const vf2 js3 = mkv(-sgn*s3.y, sgn*s3.x);
            u[4*b+0]=s0+s2;
            u[4*b+1]=s1+js3;
            u[4*b+2]=s0-s2;
            u[4*b+3]=s1-js3;
        }
    }
    u[4+1] = mri(u[4+1],  C1, sgn*S1);
    u[4+2] = mri(u[4+2],  R,  sgn*R );
    u[4+3] = mri(u[4+3],  S1, sgn*C1);
    u[8+1] = mri(u[8+1],  R,  sgn*R );
    u[8+2] = mri(u[8+2],  0.f, sgn);
    u[8+3] = mri(u[8+3], -R,  sgn*R );
    u[12+1]= mri(u[12+1], S1, sgn*C1);
    u[12+2]= mri(u[12+2],-R,  sgn*R );
    u[12+3]= mri(u[12+3],-C1,-sgn*S1);
#pragma unroll
    for (int c=0;c<4;++c){
        const vf2 a0=u[c], a1=u[4+c], a2=u[8+c], a3=u[12+c];
        const vf2 s0=a0+a2, s1=a0-a2;
        const vf2 s2=a1+a3, s3=a1-a3;
        const vf2 js3 = mkv(-sgn*s3.y, sgn*s3.x);
        d[S*(c+0)] =s0+s2;
        d[S*(c+4)] =s1+js3;
        d[S*(c+8)] =s0-s2;
        d[S*(c+12)]=s1-js3;
    }
}

// log-depth twiddle: w[q] = w1^q via pairwise products (depth 4 vs serial 15),
// then d[q] *= w[q]. r12's serial chain was a ~60-cycle dep chain hit by all
// waves simultaneously after each barrier.
__device__ __forceinline__ void tw_apply(vf2* d, vf2 w1){
    vf2 w[16];
    w[1] = w1;
#pragma unroll
    for (int q=2;q<16;++q) w[q] = cmul(w[q>>1], w[q-(q>>1)]);
#pragma unroll
    for (int q=1;q<16;++q) d[q] = cmul(d[q], w[q]);
}
// same powers applied to d[q] and d[16+q] (shared-twiddle butterfly pair)
__device__ __forceinline__ void tw_apply2(vf2* d, vf2 w1){
    vf2 w[16];
    w[1] = w1;
#pragma unroll
    for (int q=2;q<16;++q) w[q] = cmul(w[q>>1], w[q-(q>>1)]);
#pragma unroll
    for (int q=1;q<16;++q){ d[q] = cmul(d[q], w[q]); d[16+q] = cmul(d[16+q], w[q]); }
}

// ---------------------------------------------------------------------------
// Heff, pair-based: thread handles bins (f, g=8192-f), f in [0,4096).
// Heff[f] = (H[f]+conj(H[g]))/2 / N ; Heff[g] = conj(Heff[f]) (real impulse
// response). One dot-product set serves BOTH outputs (r12 computed each twice).
// f lane-consecutive -> Wf/Wp row reads fully coalesced; c[b] wave-uniform ->
// scalar loads. Writes scattered 8B at pos_of_bin (fire-and-forget).
// ---------------------------------------------------------------------------
__global__ void h_kernel(const float* __restrict__ c,  const float* __restrict__ Wf,
                         const float* __restrict__ bfv, const float* __restrict__ Wp,
                         const float* __restrict__ bpv, float2* __restrict__ H){
    const int f = blockIdx.x*256 + threadIdx.x;   // 0..4095
    const int b = blockIdx.y;
    const int g = (FL - f) & (FL - 1);
    float amf = bfv[f], apf = bpv[f], amg = bfv[g], apg = bpv[g];
#pragma unroll
    for (int i=0;i<CD;++i){
        const float cv = c[b*CD + i];
        amf += cv * Wf[f*CD + i];
        apf += cv * Wp[f*CD + i];
        amg += cv * Wf[g*CD + i];
        apg += cv * Wp[g*CD + i];
    }
    const float magf = 1.f/(1.f+__expf(-amf));
    const float magg = 1.f/(1.f+__expf(-amg));
    float sf, cf2, sg, cg2;
    __sincosf(apf, &sf, &cf2);
    __sincosf(apg, &sg, &cg2);
    const float scale = 0.5f / (float)FL;
    const float re = (magf*cf2 + magg*cg2)*scale;
    const float im = (magf*sf  - magg*sg )*scale;
    float2* Hb = H + (size_t)b*FL;
    Hb[pos_of_bin(f)] = make_float2(re,  im);
    Hb[pos_of_bin(g)] = make_float2(re, -im);
    if (f == 0){
        // bin 4096 self-pair: Heff[4096] = Re(H[4096]) / N
        float am = bfv[4096], ap = bpv[4096];
#pragma unroll
        for (int i=0;i<CD;++i){
            const float cv = c[b*CD + i];
            am += cv * Wf[4096*CD + i];
            ap += cv * Wp[4096*CD + i];
        }
        const float mag = 1.f/(1.f+__expf(-am));
        Hb[pos_of_bin(4096)] = make_float2(mag*__cosf(ap)*(2.f*scale), 0.f);
    }
}

// ---------------------------------------------------------------------------
// One WG (256 thr x 32 elements) per (block-pair, batch).
// A : global->reg, 2x DFT16(half, j=t & t+256), tw W_8192^{jq}, ->LDS (s512)
//     second twiddle base = first * e^{-i pi/16} (one sincos, not two)
// B : 2x DFT16 (groups g,g+8; SHARED twiddle W_512^{j2 q})          (s32)
// E : contiguous 32-block: DFT32 (even/odd DIT, const W32) x Heff x IDFT32
// B', A': mirrors with positive-angle twiddles.
// LDS layout: block stride 33 (addr = 33*(e>>5) + (e&31)); all passes 2-way.
// launch_bounds(256,3): ~170 VGPR budget -- avoids the 64-cap spill trap.
// ---------------------------------------------------------------------------
__global__ __launch_bounds__(256, 3) void fft_kernel(const float*  __restrict__ x,
                                                     const float2* __restrict__ H,
                                                     float* __restrict__ out){
    extern __shared__ __half2 buf[];     // 8448 * 4B = 33 KiB
    const int t  = threadIdx.x;          // 0..255
    const int pr = blockIdx.x;
    const int b  = blockIdx.y;
    const float* xb = x + (size_t)b*SEQ;
    const int s0 = 2*pr*BS - (FL-1);
    const float TWO_PI = 6.28318530717958647692f;

    vf2 d[32];

    constexpr float CT[16] = { 1.f, 0.980785280403230f, 0.923879532511287f, 0.831469612302545f,
                               0.707106781186548f, 0.555570233019602f, 0.382683432365090f, 0.195090322016128f,
                               0.f,-0.195090322016128f,-0.382683432365090f,-0.555570233019602f,
                              -0.707106781186548f,-0.831469612302545f,-0.923879532511287f,-0.980785280403230f };
    constexpr float ST[16] = { 0.f, 0.195090322016128f, 0.382683432365090f, 0.555570233019602f,
                               0.707106781186548f, 0.831469612302545f, 0.923879532511287f, 0.980785280403230f,
                               1.f, 0.980785280403230f, 0.923879532511287f, 0.831469612302545f,
                               0.707106781186548f, 0.555570233019602f, 0.382683432365090f, 0.195090322016128f };

    const int pa0 = t + (t>>5);          // padded addr of j=t
    // padded addr of j=t+256 is pa0 + 264  (256 + 8 pad)

    // ---- Pass A: radix-16, stride 512; butterflies j=t and j=t+256 ----
    {
        if (pr == 0){
#pragma unroll
            for (int h=0; h<2; ++h){
                const int j = t + 256*h;
#pragma unroll
                for (int m=0;m<8;++m){
                    const int k  = j + 512*m;
                    const int ua = s0 + k, ub = ua + BS;
                    const float va = (ua >= 0) ? xb[ua] : 0.f;
                    const float vb = (ub >= 0) ? xb[ub] : 0.f;
                    d[16*h + m] = mkv(va, vb);
                }
            }
        } else {
            const float* bp = xb + s0;
#pragma unroll
            for (int h=0; h<2; ++h){
                const int j = t + 256*h;
#pragma unroll
                for (int m=0;m<8;++m){
                    const int k = j + 512*m;
                    d[16*h + m] = mkv(bp[k], bp[k + BS]);
                }
            }
        }
        dft16<false,true,1>(d);
        dft16<false,true,1>(d+16);
        float sn, cs; __sincosf(-TWO_PI * (float)t / 8192.f, &sn, &cs);
        const vf2 w0 = mkv(cs, sn);
        tw_apply(d,    w0);
        tw_apply(d+16, cmul(w0, mkv(0.980785280403230f, -0.195090322016128f))); // * e^{-i pi/16}
#pragma unroll
        for (int q=0;q<16;++q){
            sth(buf, pa0       + 528*q, d[q]);
            sth(buf, pa0 + 264 + 528*q, d[16+q]);
        }
    }
    __syncthreads();

    // ---- Pass B: radix-16, stride 32; groups g=t>>5 and g+8, shared j2 ----
    {
        const int j2 = t & 31;
        const int a0 = 528*(t>>5) + j2;    // group g
        const int a1 = a0 + 4224;          // group g+8 (528*8)
#pragma unroll
        for (int m=0;m<16;++m){
            d[m]    = ldh(buf, a0 + 33*m);
            d[16+m] = ldh(buf, a1 + 33*m);
        }
        dft16<false,false,1>(d);
        dft16<false,false,1>(d+16);
        float sn, cs; __sincosf(-TWO_PI * (float)j2 / 512.f, &sn, &cs);
        tw_apply2(d, mkv(cs, sn));
#pragma unroll
        for (int q=0;q<16;++q){
            sth(buf, a0 + 33*q, d[q]);
            sth(buf, a1 + 33*q, d[16+q]);
        }
    }
    __syncthreads();

    // ---- Pass E: contiguous 32-block t: DFT32 x Heff x IDFT32 ----
    {
        const int a0 = 33*t;
#pragma unroll
        for (int i=0;i<32;++i) d[i] = ldh(buf, a0 + i);
        dft16<false,false,2>(d);       // even elems -> E[k] at d[2k]
        dft16<false,false,2>(d+1);     // odd  elems -> O[k] at d[2k+1]
        const float2* Hb = H + (size_t)b*FL + (t<<5);
#pragma unroll
        for (int w=0;w<16;++w){
            const vf2 Ow = mri(d[2*w+1], CT[w], -ST[w]);   // W32^w * O[w]
            const vf2 Ew = d[2*w];
            vf2 Xlo = Ew + Ow;                             // bin w
            vf2 Xhi = Ew - Ow;                             // bin w+16
            const float2 h0 = Hb[w], h1 = Hb[w+16];
            Xlo = cmul(Xlo, mkv(h0.x, h0.y));
            Xhi = cmul(Xhi, mkv(h1.x, h1.y));
            d[2*w]   = Xlo + Xhi;                          // A_w
            d[2*w+1] = mri(Xlo - Xhi, CT[w], ST[w]);       // B_w = (Xlo-Xhi)*conj(W32^w)
        }
        dft16<true,false,2>(d);        // y[2i]   at d[2i]
        dft16<true,false,2>(d+1);      // y[2i+1] at d[2i+1]
#pragma unroll
        for (int i=0;i<32;++i) sth(buf, a0 + i, d[i]);
    }
    __syncthreads();

    // ---- Pass B': inverse radix-16, stride 32 (positive-angle twiddles) ----
    {
        const int j2 = t & 31;
        const int a0 = 528*(t>>5) + j2;
        const int a1 = a0 + 4224;
#pragma unroll
        for (int q=0;q<16;++q){
            d[q]    = ldh(buf, a0 + 33*q);
            d[16+q] = ldh(buf, a1 + 33*q);
        }
        float sn, cs; __sincosf(TWO_PI * (float)j2 / 512.f, &sn, &cs);
        tw_apply2(d, mkv(cs, sn));
        dft16<true,false,1>(d);
        dft16<true,false,1>(d+16);
#pragma unroll
        for (int m=0;m<16;++m){
            sth(buf, a0 + 33*m, d[m]);
            sth(buf, a1 + 33*m, d[16+m]);
        }
    }
    __syncthreads();

    // ---- Pass A': inverse radix-16, stride 512; direct overlap-add ----
    {
#pragma unroll
        for (int q=0;q<16;++q){
            d[q]    = ldh(buf, pa0       + 528*q);
            d[16+q] = ldh(buf, pa0 + 264 + 528*q);
        }
        float sn, cs; __sincosf(TWO_PI * (float)t / 8192.f, &sn, &cs);
        const vf2 w0 = mkv(cs, sn);
        tw_apply(d,    w0);
        tw_apply(d+16, cmul(w0, mkv(0.980785280403230f, 0.195090322016128f))); // * e^{+i pi/16}
        dft16<true,false,1>(d);
        dft16<true,false,1>(d+16);
        // d[16h+m] = y[time (t+256h) + 512m]; Re -> block a, Im -> block b.
        float* ob = out + (size_t)b*SEQ;
        const int pa = 2*pr*BS;
        const bool last = (pr == NPAIR-1);
#pragma unroll
        for (int h=0; h<2; ++h){
            const int j = t + 256*h;
#pragma unroll
            for (int mm=0;mm<8;++mm){
                const int klo = j + 512*mm;                      // 0..4095
                const vf2 ylo = d[16*h + mm];
                const vf2 yhi = d[16*h + mm + 8];
                atomicAdd(&ob[pa+klo], ylo.x);                   // even span (2 writers)
                ob[pa+BS+klo] = yhi.x + ylo.y;                   // odd span (sole writer)
                if (!last) atomicAdd(&ob[pa+2*BS+klo], yhi.y);   // even span (2 writers)
            }
        }
    }
}

// ---------------------------------------------------------------------------
extern "C" void kernel_launch(void* const* d_in, const int* in_sizes, int n_in,
                              void* d_out, int out_size, void* d_ws, size_t ws_size,
                              hipStream_t stream) {
    const float* x   = (const float*)d_in[0];
    const float* c   = (const float*)d_in[1];
    const float* Wf  = (const float*)d_in[2];
    const float* bfv = (const float*)d_in[3];
    const float* Wp  = (const float*)d_in[4];
    const float* bpv = (const float*)d_in[5];

    float*  out = (float*)d_out;
    float2* H   = (float2*)d_ws;                      // BATCH*FL*8B = 2 MiB

    hipMemsetAsync(d_out, 0, (size_t)out_size*sizeof(float), stream);
    h_kernel<<<dim3(FL/2/256, BATCH), 256, 0, stream>>>(c, Wf, bfv, Wp, bpv, H);
    fft_kernel<<<dim3(NPAIR, BATCH), 256, LDSN*sizeof(__half2), stream>>>(x, H, out);
}

// Round 15
// 57.612 us; speedup vs baseline: 2.5852x; 1.0786x over previous
//
#include <hip/hip_runtime.h>
#include <hip/hip_fp16.h>
#include <math.h>

#define FL     8192
#define BS     4096      // block step = FL/2
#define CD     16
#define BATCH  32
#define SEQ    262144
#define NPAIR  32        // 64 blocks -> 32 pairs
#define LDSN   8448      // 256 blocks * 33 (32 + 1 pad)

// Packed fp32 complex: <2 x float> -> v_pk_add_f32 / v_pk_fma_f32 on gfx950.
typedef float vf2 __attribute__((ext_vector_type(2)));
__device__ __forceinline__ vf2 mkv(float x, float y){ vf2 v; v.x = x; v.y = y; return v; }
__device__ __forceinline__ vf2 cmul(vf2 a, vf2 b){            // a * b
    const vf2 c = mkv(-a.y, a.x) * mkv(b.y, b.y);
    return a * mkv(b.x, b.x) + c;
}
__device__ __forceinline__ vf2 mri(vf2 a, float c, float s){  // a * (c + i s)
    const vf2 t = mkv(-a.y, a.x) * mkv(s, s);
    return a * mkv(c, c) + t;
}

// fp16 LDS staging (addresses are PRE-PADDED by caller)
__device__ __forceinline__ void sth(__half2* buf, int i, vf2 v){ buf[i] = __floats2half2_rn(v.x, v.y); }
__device__ __forceinline__ vf2 ldh(const __half2* buf, int i){ const float2 f = __half22float2(buf[i]); return mkv(f.x, f.y); }

// flat position p <-> natural bin k maps for passes A(R16,s512),B(R16,s32),E(32-block)
// p = 512*qA + 32*qB + w  <->  k = qA + 16*qB + 256*w
__device__ __forceinline__ int pos_of_bin(int k){
    return ((k&15)<<9) | (((k>>4)&15)<<5) | (k>>8);
}

// ---------------------------------------------------------------------------
// In-register 16-point DFT over d[S*0..S*15], 4x4 Cooley-Tukey.
// INV: conjugate (inverse, unnormalized). HALF: inputs d[S*8..S*15] are zero.
// ---------------------------------------------------------------------------
template<bool INV, bool HALF, int S>
__device__ __forceinline__ void dft16(vf2* d){
    constexpr float sgn = INV ? 1.f : -1.f;          // e^{sgn*i*2pi*k/16}
    constexpr float C1 = 0.923879532511287f;          // cos(pi/8)
    constexpr float S1 = 0.382683432365090f;          // sin(pi/8)
    constexpr float R  = 0.707106781186548f;
    vf2 u[16];
#pragma unroll
    for (int b=0;b<4;++b){
        const vf2 a0=d[S*b], a1=d[S*(4+b)];
        if (HALF){
            const vf2 ja1 = mkv(-sgn*a1.y, sgn*a1.x);
            u[4*b+0]=a0+a1;
            u[4*b+1]=a0+ja1;
            u[4*b+2]=a0-a1;
            u[4*b+3]=a0-ja1;
        } else {
            const vf2 a2=d[S*(8+b)], a3=d[S*(12+b)];
            const vf2 s0=a0+a2, s1=a0-a2;
            const vf2 s2=a1+a3, s3=a1-a3;
            const vf2 js3 = mkv(-sgn*s3.y, sgn*s3.x);
            u[4*b+0]=s0+s2;
            u[4*b+1]=s1+js3;
            u[4*b+2]=s0-s2;
            u[4*b+3]=s1-js3;
        }
    }
    u[4+1] = mri(u[4+1],  C1, sgn*S1);
    u[4+2] = mri(u[4+2],  R,  sgn*R );
    u[4+3] = mri(u[4+3],  S1, sgn*C1);
    u[8+1] = mri(u[8+1],  R,  sgn*R );
    u[8+2] = mri(u[8+2],  0.f, sgn);
    u[8+3] = mri(u[8+3], -R,  sgn*R );
    u[12+1]= mri(u[12+1], S1, sgn*C1);
    u[12+2]= mri(u[12+2],-R,  sgn*R );
    u[12+3]= mri(u[12+3],-C1,-sgn*S1);
#pragma unroll
    for (int c=0;c<4;++c){
        const vf2 a0=u[c], a1=u[4+c], a2=u[8+c], a3=u[12+c];
        const vf2 s0=a0+a2, s1=a0-a2;
        const vf2 s2=a1+a3, s3=a1-a3;
        const vf2 js3 = mkv(-sgn*s3.y, sgn*s3.x);
        d[S*(c+0)] =s0+s2;
        d[S*(c+4)] =s1+js3;
        d[S*(c+8)] =s0-s2;
        d[S*(c+12)]=s1-js3;
    }
}

// log-depth twiddle: w[q] = w1^q via pairwise products (depth 4), d[q] *= w[q].
__device__ __forceinline__ void tw_apply(vf2* d, vf2 w1){
    vf2 w[16];
    w[1] = w1;
#pragma unroll
    for (int q=2;q<16;++q) w[q] = cmul(w[q>>1], w[q-(q>>1)]);
#pragma unroll
    for (int q=1;q<16;++q) d[q] = cmul(d[q], w[q]);
}
// same powers applied to d[q] and d[16+q] (shared-twiddle butterfly pair)
__device__ __forceinline__ void tw_apply2(vf2* d, vf2 w1){
    vf2 w[16];
    w[1] = w1;
#pragma unroll
    for (int q=2;q<16;++q) w[q] = cmul(w[q>>1], w[q-(q>>1)]);
#pragma unroll
    for (int q=1;q<16;++q){ d[q] = cmul(d[q], w[q]); d[16+q] = cmul(d[16+q], w[q]); }
}

// ---------------------------------------------------------------------------
// Heff pair-based + FUSED OUTPUT ZEROING (replaces the hipMemsetAsync dispatch;
// zero-stores are fire-and-forget and hide under the dot-product/sincos VALU).
// Thread handles bins (f, g=8192-f): one dot-product set serves both outputs;
// Wf/Wp reads coalesced; c[b] wave-uniform.
// ---------------------------------------------------------------------------
__global__ void h_kernel(const float* __restrict__ c,  const float* __restrict__ Wf,
                         const float* __restrict__ bfv, const float* __restrict__ Wp,
                         const float* __restrict__ bpv, float2* __restrict__ H,
                         float4* __restrict__ outz){
    const int f = blockIdx.x*256 + threadIdx.x;   // 0..4095
    const int b = blockIdx.y;
    const int g = (FL - f) & (FL - 1);

    // ---- fused zeroing of out: 512 blocks x 256 thr x 16 float4 = 33.5 MB ----
    {
        const int gtid = (blockIdx.y*gridDim.x + blockIdx.x)*256 + threadIdx.x; // 0..131071
        const float4 z = make_float4(0.f,0.f,0.f,0.f);
#pragma unroll
        for (int i=0;i<16;++i) outz[gtid + i*131072] = z;
    }

    float amf = bfv[f], apf = bpv[f], amg = bfv[g], apg = bpv[g];
#pragma unroll
    for (int i=0;i<CD;++i){
        const float cv = c[b*CD + i];
        amf += cv * Wf[f*CD + i];
        apf += cv * Wp[f*CD + i];
        amg += cv * Wf[g*CD + i];
        apg += cv * Wp[g*CD + i];
    }
    const float magf = 1.f/(1.f+__expf(-amf));
    const float magg = 1.f/(1.f+__expf(-amg));
    float sf, cf2, sg, cg2;
    __sincosf(apf, &sf, &cf2);
    __sincosf(apg, &sg, &cg2);
    const float scale = 0.5f / (float)FL;
    const float re = (magf*cf2 + magg*cg2)*scale;
    const float im = (magf*sf  - magg*sg )*scale;
    float2* Hb = H + (size_t)b*FL;
    Hb[pos_of_bin(f)] = make_float2(re,  im);
    Hb[pos_of_bin(g)] = make_float2(re, -im);
    if (f == 0){
        // bin 4096 self-pair: Heff[4096] = Re(H[4096]) / N
        float am = bfv[4096], ap = bpv[4096];
#pragma unroll
        for (int i=0;i<CD;++i){
            const float cv = c[b*CD + i];
            am += cv * Wf[4096*CD + i];
            ap += cv * Wp[4096*CD + i];
        }
        const float mag = 1.f/(1.f+__expf(-am));
        Hb[pos_of_bin(4096)] = make_float2(mag*__cosf(ap)*(2.f*scale), 0.f);
    }
}

// ---------------------------------------------------------------------------
// One WG (256 thr x 32 elements) per (block-pair, batch).
// A : global->reg, 2x DFT16(half, j=t & t+256), tw W_8192^{jq}, ->LDS (s512)
// B : 2x DFT16 (groups g,g+8; SHARED twiddle W_512^{j2 q})          (s32)
// E : contiguous 32-block: DFT32 (even/odd DIT, const W32) x Heff x IDFT32
// B', A': mirrors with positive-angle twiddles.
// LDS layout: block stride 33 (addr = 33*(e>>5) + (e&31)); conflicts = 0 (r13).
// launch_bounds(256,3): 56 VGPR, no spill (r12/r13 verified).
// ---------------------------------------------------------------------------
__global__ __launch_bounds__(256, 3) void fft_kernel(const float*  __restrict__ x,
                                                     const float2* __restrict__ H,
                                                     float* __restrict__ out){
    extern __shared__ __half2 buf[];     // 8448 * 4B = 33 KiB
    const int t  = threadIdx.x;          // 0..255
    const int pr = blockIdx.x;
    const int b  = blockIdx.y;
    const float* xb = x + (size_t)b*SEQ;
    const int s0 = 2*pr*BS - (FL-1);
    const float TWO_PI = 6.28318530717958647692f;

    vf2 d[32];

    constexpr float CT[16] = { 1.f, 0.980785280403230f, 0.923879532511287f, 0.831469612302545f,
                               0.707106781186548f, 0.555570233019602f, 0.382683432365090f, 0.195090322016128f,
                               0.f,-0.195090322016128f,-0.382683432365090f,-0.555570233019602f,
                              -0.707106781186548f,-0.831469612302545f,-0.923879532511287f,-0.980785280403230f };
    constexpr float ST[16] = { 0.f, 0.195090322016128f, 0.382683432365090f, 0.555570233019602f,
                               0.707106781186548f, 0.831469612302545f, 0.923879532511287f, 0.980785280403230f,
                               1.f, 0.980785280403230f, 0.923879532511287f, 0.831469612302545f,
                               0.707106781186548f, 0.555570233019602f, 0.382683432365090f, 0.195090322016128f };

    const int pa0 = t + (t>>5);          // padded addr of j=t
    // padded addr of j=t+256 is pa0 + 264  (256 + 8 pad)

    // ---- Pass A: radix-16, stride 512; butterflies j=t and j=t+256 ----
    {
        if (pr == 0){
#pragma unroll
            for (int h=0; h<2; ++h){
                const int j = t + 256*h;
#pragma unroll
                for (int m=0;m<8;++m){
                    const int k  = j + 512*m;
                    const int ua = s0 + k, ub = ua + BS;
                    const float va = (ua >= 0) ? xb[ua] : 0.f;
                    const float vb = (ub >= 0) ? xb[ub] : 0.f;
                    d[16*h + m] = mkv(va, vb);
                }
            }
        } else {
            const float* bp = xb + s0;
#pragma unroll
            for (int h=0; h<2; ++h){
                const int j = t + 256*h;
#pragma unroll
                for (int m=0;m<8;++m){
                    const int k = j + 512*m;
                    d[16*h + m] = mkv(bp[k], bp[k + BS]);
                }
            }
        }
        dft16<false,true,1>(d);
        dft16<false,true,1>(d+16);
        float sn, cs; __sincosf(-TWO_PI * (float)t / 8192.f, &sn, &cs);
        const vf2 w0 = mkv(cs, sn);
        tw_apply(d,    w0);
        tw_apply(d+16, cmul(w0, mkv(0.980785280403230f, -0.195090322016128f))); // * e^{-i pi/16}
#pragma unroll
        for (int q=0;q<16;++q){
            sth(buf, pa0       + 528*q, d[q]);
            sth(buf, pa0 + 264 + 528*q, d[16+q]);
        }
    }
    __syncthreads();

    // ---- Pass B: radix-16, stride 32; groups g=t>>5 and g+8, shared j2 ----
    {
        const int j2 = t & 31;
        const int a0 = 528*(t>>5) + j2;    // group g
        const int a1 = a0 + 4224;          // group g+8 (528*8)
#pragma unroll
        for (int m=0;m<16;++m){
            d[m]    = ldh(buf, a0 + 33*m);
            d[16+m] = ldh(buf, a1 + 33*m);
        }
        dft16<false,false,1>(d);
        dft16<false,false,1>(d+16);
        float sn, cs; __sincosf(-TWO_PI * (float)j2 / 512.f, &sn, &cs);
        tw_apply2(d, mkv(cs, sn));
#pragma unroll
        for (int q=0;q<16;++q){
            sth(buf, a0 + 33*q, d[q]);
            sth(buf, a1 + 33*q, d[16+q]);
        }
    }
    __syncthreads();

    // ---- Pass E: contiguous 32-block t: DFT32 x Heff x IDFT32 ----
    {
        const int a0 = 33*t;
#pragma unroll
        for (int i=0;i<32;++i) d[i] = ldh(buf, a0 + i);
        dft16<false,false,2>(d);       // even elems -> E[k] at d[2k]
        dft16<false,false,2>(d+1);     // odd  elems -> O[k] at d[2k+1]
        const float2* Hb = H + (size_t)b*FL + (t<<5);
#pragma unroll
        for (int w=0;w<16;++w){
            const vf2 Ow = mri(d[2*w+1], CT[w], -ST[w]);   // W32^w * O[w]
            const vf2 Ew = d[2*w];
            vf2 Xlo = Ew + Ow;                             // bin w
            vf2 Xhi = Ew - Ow;                             // bin w+16
            const float2 h0 = Hb[w], h1 = Hb[w+16];
            Xlo = cmul(Xlo, mkv(h0.x, h0.y));
            Xhi = cmul(Xhi, mkv(h1.x, h1.y));
            d[2*w]   = Xlo + Xhi;                          // A_w
            d[2*w+1] = mri(Xlo - Xhi, CT[w], ST[w]);       // B_w = (Xlo-Xhi)*conj(W32^w)
        }
        dft16<true,false,2>(d);        // y[2i]   at d[2i]
        dft16<true,false,2>(d+1);      // y[2i+1] at d[2i+1]
#pragma unroll
        for (int i=0;i<32;++i) sth(buf, a0 + i, d[i]);
    }
    __syncthreads();

    // ---- Pass B': inverse radix-16, stride 32 (positive-angle twiddles) ----
    {
        const int j2 = t & 31;
        const int a0 = 528*(t>>5) + j2;
        const int a1 = a0 + 4224;
#pragma unroll
        for (int q=0;q<16;++q){
            d[q]    = ldh(buf, a0 + 33*q);
            d[16+q] = ldh(buf, a1 + 33*q);
        }
        float sn, cs; __sincosf(TWO_PI * (float)j2 / 512.f, &sn, &cs);
        tw_apply2(d, mkv(cs, sn));
        dft16<true,false,1>(d);
        dft16<true,false,1>(d+16);
#pragma unroll
        for (int m=0;m<16;++m){
            sth(buf, a0 + 33*m, d[m]);
            sth(buf, a1 + 33*m, d[16+m]);
        }
    }
    __syncthreads();

    // ---- Pass A': inverse radix-16, stride 512; direct overlap-add ----
    {
#pragma unroll
        for (int q=0;q<16;++q){
            d[q]    = ldh(buf, pa0       + 528*q);
            d[16+q] = ldh(buf, pa0 + 264 + 528*q);
        }
        float sn, cs; __sincosf(TWO_PI * (float)t / 8192.f, &sn, &cs);
        const vf2 w0 = mkv(cs, sn);
        tw_apply(d,    w0);
        tw_apply(d+16, cmul(w0, mkv(0.980785280403230f, 0.195090322016128f))); // * e^{+i pi/16}
        dft16<true,false,1>(d);
        dft16<true,false,1>(d+16);
        // d[16h+m] = y[time (t+256h) + 512m]; Re -> block a, Im -> block b.
        float* ob = out + (size_t)b*SEQ;
        const int pa = 2*pr*BS;
        const bool last = (pr == NPAIR-1);
#pragma unroll
        for (int h=0; h<2; ++h){
            const int j = t + 256*h;
#pragma unroll
            for (int mm=0;mm<8;++mm){
                const int klo = j + 512*mm;                      // 0..4095
                const vf2 ylo = d[16*h + mm];
                const vf2 yhi = d[16*h + mm + 8];
                atomicAdd(&ob[pa+klo], ylo.x);                   // even span (2 writers)
                ob[pa+BS+klo] = yhi.x + ylo.y;                   // odd span (sole writer)
                if (!last) atomicAdd(&ob[pa+2*BS+klo], yhi.y);   // even span (2 writers)
            }
        }
    }
}

// ---------------------------------------------------------------------------
extern "C" void kernel_launch(void* const* d_in, const int* in_sizes, int n_in,
                              void* d_out, int out_size, void* d_ws, size_t ws_size,
                              hipStream_t stream) {
    const float* x   = (const float*)d_in[0];
    const float* c   = (const float*)d_in[1];
    const float* Wf  = (const float*)d_in[2];
    const float* bfv = (const float*)d_in[3];
    const float* Wp  = (const float*)d_in[4];
    const float* bpv = (const float*)d_in[5];

    float*  out = (float*)d_out;
    float2* H   = (float2*)d_ws;                      // BATCH*FL*8B = 2 MiB

    // h_kernel also zeroes `out` (fused memset) -> fft sees zeroed buffer.
    h_kernel<<<dim3(FL/2/256, BATCH), 256, 0, stream>>>(c, Wf, bfv, Wp, bpv, H,
                                                        (float4*)d_out);
    fft_kernel<<<dim3(NPAIR, BATCH), 256, LDSN*sizeof(__half2), stream>>>(x, H, out);
}

// Round 16
// 56.646 us; speedup vs baseline: 2.6293x; 1.0171x over previous
//
#include <hip/hip_runtime.h>
#include <hip/hip_fp16.h>
#include <math.h>

#define FL     8192
#define BS     4096      // block step = FL/2
#define CD     16
#define BATCH  32
#define SEQ    262144
#define NPAIR  32        // 64 blocks -> 32 pairs
#define BSTR   36        // LDS block stride (32 elems + 4 pad) -> 144B, 16B-aligned
#define LDSN   (256*BSTR) // 9216 half2 = 36 KiB

// Packed fp32 complex: <2 x float> -> v_pk_add_f32 / v_pk_fma_f32 on gfx950.
typedef float vf2 __attribute__((ext_vector_type(2)));
__device__ __forceinline__ vf2 mkv(float x, float y){ vf2 v; v.x = x; v.y = y; return v; }
__device__ __forceinline__ vf2 cmul(vf2 a, vf2 b){            // a * b
    const vf2 c = mkv(-a.y, a.x) * mkv(b.y, b.y);
    return a * mkv(b.x, b.x) + c;
}
__device__ __forceinline__ vf2 mri(vf2 a, float c, float s){  // a * (c + i s)
    const vf2 t = mkv(-a.y, a.x) * mkv(s, s);
    return a * mkv(c, c) + t;
}

// fp16 LDS staging (addresses are PRE-PADDED by caller)
__device__ __forceinline__ void sth(__half2* buf, int i, vf2 v){ buf[i] = __floats2half2_rn(v.x, v.y); }
__device__ __forceinline__ vf2 ldh(const __half2* buf, int i){ const float2 f = __half22float2(buf[i]); return mkv(f.x, f.y); }
// uint <-> fp16x2 for vectorized (b128) LDS access in pass E
__device__ __forceinline__ vf2 h2f(unsigned u){ const float2 f = __half22float2(__builtin_bit_cast(__half2, u)); return mkv(f.x, f.y); }
__device__ __forceinline__ unsigned f2h(vf2 v){ return __builtin_bit_cast(unsigned, __floats2half2_rn(v.x, v.y)); }

// flat position p <-> natural bin k maps for passes A(R16,s512),B(R16,s32),E(32-block)
// p = 512*qA + 32*qB + w  <->  k = qA + 16*qB + 256*w   (logical, unpadded)
__device__ __forceinline__ int pos_of_bin(int k){
    return ((k&15)<<9) | (((k>>4)&15)<<5) | (k>>8);
}

// ---------------------------------------------------------------------------
// In-register 16-point DFT over d[S*0..S*15], 4x4 Cooley-Tukey.
// INV: conjugate (inverse, unnormalized). HALF: inputs d[S*8..S*15] are zero.
// ---------------------------------------------------------------------------
template<bool INV, bool HALF, int S>
__device__ __forceinline__ void dft16(vf2* d){
    constexpr float sgn = INV ? 1.f : -1.f;          // e^{sgn*i*2pi*k/16}
    constexpr float C1 = 0.923879532511287f;          // cos(pi/8)
    constexpr float S1 = 0.382683432365090f;          // sin(pi/8)
    constexpr float R  = 0.707106781186548f;
    vf2 u[16];
#pragma unroll
    for (int b=0;b<4;++b){
        const vf2 a0=d[S*b], a1=d[S*(4+b)];
        if (HALF){
            const vf2 ja1 = mkv(-sgn*a1.y, sgn*a1.x);
            u[4*b+0]=a0+a1;
            u[4*b+1]=a0+ja1;
            u[4*b+2]=a0-a1;
            u[4*b+3]=a0-ja1;
        } else {
            const vf2 a2=d[S*(8+b)], a3=d[S*(12+b)];
            const vf2 s0=a0+a2, s1=a0-a2;
            const vf2 s2=a1+a3, s3=a1-a3;
            const vf2 js3 = mkv(-sgn*s3.y, sgn*s3.x);
            u[4*b+0]=s0+s2;
            u[4*b+1]=s1+js3;
            u[4*b+2]=s0-s2;
            u[4*b+3]=s1-js3;
        }
    }
    u[4+1] = mri(u[4+1],  C1, sgn*S1);
    u[4+2] = mri(u[4+2],  R,  sgn*R );
    u[4+3] = mri(u[4+3],  S1, sgn*C1);
    u[8+1] = mri(u[8+1],  R,  sgn*R );
    u[8+2] = mri(u[8+2],  0.f, sgn);
    u[8+3] = mri(u[8+3], -R,  sgn*R );
    u[12+1]= mri(u[12+1], S1, sgn*C1);
    u[12+2]= mri(u[12+2],-R,  sgn*R );
    u[12+3]= mri(u[12+3],-C1,-sgn*S1);
#pragma unroll
    for (int c=0;c<4;++c){
        const vf2 a0=u[c], a1=u[4+c], a2=u[8+c], a3=u[12+c];
        const vf2 s0=a0+a2, s1=a0-a2;
        const vf2 s2=a1+a3, s3=a1-a3;
        const vf2 js3 = mkv(-sgn*s3.y, sgn*s3.x);
        d[S*(c+0)] =s0+s2;
        d[S*(c+4)] =s1+js3;
        d[S*(c+8)] =s0-s2;
        d[S*(c+12)]=s1-js3;
    }
}

// log-depth twiddle: w[q] = w1^q via pairwise products (depth 4), d[q] *= w[q].
__device__ __forceinline__ void tw_apply(vf2* d, vf2 w1){
    vf2 w[16];
    w[1] = w1;
#pragma unroll
    for (int q=2;q<16;++q) w[q] = cmul(w[q>>1], w[q-(q>>1)]);
#pragma unroll
    for (int q=1;q<16;++q) d[q] = cmul(d[q], w[q]);
}
// same powers applied to d[q] and d[16+q] (shared-twiddle butterfly pair)
__device__ __forceinline__ void tw_apply2(vf2* d, vf2 w1){
    vf2 w[16];
    w[1] = w1;
#pragma unroll
    for (int q=2;q<16;++q) w[q] = cmul(w[q>>1], w[q-(q>>1)]);
#pragma unroll
    for (int q=1;q<16;++q){ d[q] = cmul(d[q], w[q]); d[16+q] = cmul(d[16+q], w[q]); }
}

// ---------------------------------------------------------------------------
// Heff pair-based + fused zeroing of EVEN output spans only (odd spans are
// sole-writer plain-stores in fft_kernel and need no zeroing). 16.7 MB vs
// r15's 33.5 MB.
// ---------------------------------------------------------------------------
__global__ void h_kernel(const float* __restrict__ c,  const float* __restrict__ Wf,
                         const float* __restrict__ bfv, const float* __restrict__ Wp,
                         const float* __restrict__ bpv, float2* __restrict__ H,
                         float4* __restrict__ outz){
    const int f = blockIdx.x*256 + threadIdx.x;   // 0..4095
    const int b = blockIdx.y;
    const int g = (FL - f) & (FL - 1);

    // ---- zero even spans: 131072 thr x 8 float4 = 16.7 MB (coalesced) ----
    {
        const int gtid = (blockIdx.y*gridDim.x + blockIdx.x)*256 + threadIdx.x; // 0..131071
        const float4 z = make_float4(0.f,0.f,0.f,0.f);
#pragma unroll
        for (int k=0;k<8;++k){
            const int i  = gtid + k*131072;              // i-th even-span float4
            const int ei = ((i>>10)<<11) | (i&1023);     // span(ei)=2*(i>>10): even
            outz[ei] = z;
        }
    }

    float amf = bfv[f], apf = bpv[f], amg = bfv[g], apg = bpv[g];
#pragma unroll
    for (int i=0;i<CD;++i){
        const float cv = c[b*CD + i];
        amf += cv * Wf[f*CD + i];
        apf += cv * Wp[f*CD + i];
        amg += cv * Wf[g*CD + i];
        apg += cv * Wp[g*CD + i];
    }
    const float magf = 1.f/(1.f+__expf(-amf));
    const float magg = 1.f/(1.f+__expf(-amg));
    float sf, cf2, sg, cg2;
    __sincosf(apf, &sf, &cf2);
    __sincosf(apg, &sg, &cg2);
    const float scale = 0.5f / (float)FL;
    const float re = (magf*cf2 + magg*cg2)*scale;
    const float im = (magf*sf  - magg*sg )*scale;
    float2* Hb = H + (size_t)b*FL;
    Hb[pos_of_bin(f)] = make_float2(re,  im);
    Hb[pos_of_bin(g)] = make_float2(re, -im);
    if (f == 0){
        // bin 4096 self-pair: Heff[4096] = Re(H[4096]) / N
        float am = bfv[4096], ap = bpv[4096];
#pragma unroll
        for (int i=0;i<CD;++i){
            const float cv = c[b*CD + i];
            am += cv * Wf[4096*CD + i];
            ap += cv * Wp[4096*CD + i];
        }
        const float mag = 1.f/(1.f+__expf(-am));
        Hb[pos_of_bin(4096)] = make_float2(mag*__cosf(ap)*(2.f*scale), 0.f);
    }
}

// ---------------------------------------------------------------------------
// One WG (256 thr x 32 elements) per (block-pair, batch).
// LDS layout: addr(e) = 36*(e>>5) + (e&31) -- 144B block stride, 16B-aligned,
// so pass E runs on uint4 (ds_read_b128/ds_write_b128, 8+8 per thread instead
// of 64+64 b32). Passes A/B verified 2-way-bank (576 = 0 mod 32).
// launch_bounds(256,3): 56 VGPR, no spill (r12-r15 verified).
// ---------------------------------------------------------------------------
__global__ __launch_bounds__(256, 3) void fft_kernel(const float*  __restrict__ x,
                                                     const float2* __restrict__ H,
                                                     float* __restrict__ out){
    extern __shared__ __half2 buf[];     // 9216 * 4B = 36 KiB
    const int t  = threadIdx.x;          // 0..255
    const int pr = blockIdx.x;
    const int b  = blockIdx.y;
    const float* xb = x + (size_t)b*SEQ;
    const int s0 = 2*pr*BS - (FL-1);
    const float TWO_PI = 6.28318530717958647692f;

    vf2 d[32];

    constexpr float CT[16] = { 1.f, 0.980785280403230f, 0.923879532511287f, 0.831469612302545f,
                               0.707106781186548f, 0.555570233019602f, 0.382683432365090f, 0.195090322016128f,
                               0.f,-0.195090322016128f,-0.382683432365090f,-0.555570233019602f,
                              -0.707106781186548f,-0.831469612302545f,-0.923879532511287f,-0.980785280403230f };
    constexpr float ST[16] = { 0.f, 0.195090322016128f, 0.382683432365090f, 0.555570233019602f,
                               0.707106781186548f, 0.831469612302545f, 0.923879532511287f, 0.980785280403230f,
                               1.f, 0.980785280403230f, 0.923879532511287f, 0.831469612302545f,
                               0.707106781186548f, 0.555570233019602f, 0.382683432365090f, 0.195090322016128f };

    const int pa0 = BSTR*(t>>5) + (t&31);   // padded addr of element j=t
    // element j=t+256: +8 blocks -> pa0 + 288; pass-A stride 512 -> +576 per q

    // ---- Pass A: radix-16, stride 512; butterflies j=t and j=t+256 ----
    {
        if (pr == 0){
#pragma unroll
            for (int h=0; h<2; ++h){
                const int j = t + 256*h;
#pragma unroll
                for (int m=0;m<8;++m){
                    const int k  = j + 512*m;
                    const int ua = s0 + k, ub = ua + BS;
                    const float va = (ua >= 0) ? xb[ua] : 0.f;
                    const float vb = (ub >= 0) ? xb[ub] : 0.f;
                    d[16*h + m] = mkv(va, vb);
                }
            }
        } else {
            const float* bp = xb + s0;
#pragma unroll
            for (int h=0; h<2; ++h){
                const int j = t + 256*h;
#pragma unroll
                for (int m=0;m<8;++m){
                    const int k = j + 512*m;
                    d[16*h + m] = mkv(bp[k], bp[k + BS]);
                }
            }
        }
        dft16<false,true,1>(d);
        dft16<false,true,1>(d+16);
        float sn, cs; __sincosf(-TWO_PI * (float)t / 8192.f, &sn, &cs);
        const vf2 w0 = mkv(cs, sn);
        tw_apply(d,    w0);
        tw_apply(d+16, cmul(w0, mkv(0.980785280403230f, -0.195090322016128f))); // * e^{-i pi/16}
#pragma unroll
        for (int q=0;q<16;++q){
            sth(buf, pa0       + 576*q, d[q]);
            sth(buf, pa0 + 288 + 576*q, d[16+q]);
        }
    }
    __syncthreads();

    // ---- Pass B: radix-16, stride 32; groups g=t>>5 and g+8, shared j2 ----
    {
        const int j2 = t & 31;
        const int a0 = 576*(t>>5) + j2;    // group g
        const int a1 = a0 + 4608;          // group g+8 (576*8)
#pragma unroll
        for (int m=0;m<16;++m){
            d[m]    = ldh(buf, a0 + BSTR*m);
            d[16+m] = ldh(buf, a1 + BSTR*m);
        }
        dft16<false,false,1>(d);
        dft16<false,false,1>(d+16);
        float sn, cs; __sincosf(-TWO_PI * (float)j2 / 512.f, &sn, &cs);
        tw_apply2(d, mkv(cs, sn));
#pragma unroll
        for (int q=0;q<16;++q){
            sth(buf, a0 + BSTR*q, d[q]);
            sth(buf, a1 + BSTR*q, d[16+q]);
        }
    }
    __syncthreads();

    // ---- Pass E: contiguous 32-block t: DFT32 x Heff x IDFT32 (b128 LDS) ----
    {
        const uint4* __restrict__ srcv = reinterpret_cast<const uint4*>(buf + BSTR*t);
#pragma unroll
        for (int k=0;k<8;++k){
            const uint4 v = srcv[k];
            d[4*k+0] = h2f(v.x); d[4*k+1] = h2f(v.y);
            d[4*k+2] = h2f(v.z); d[4*k+3] = h2f(v.w);
        }
        dft16<false,false,2>(d);       // even elems -> E[k] at d[2k]
        dft16<false,false,2>(d+1);     // odd  elems -> O[k] at d[2k+1]
        const float2* Hb = H + (size_t)b*FL + (t<<5);
#pragma unroll
        for (int w=0;w<16;++w){
            const vf2 Ow = mri(d[2*w+1], CT[w], -ST[w]);   // W32^w * O[w]
            const vf2 Ew = d[2*w];
            vf2 Xlo = Ew + Ow;                             // bin w
            vf2 Xhi = Ew - Ow;                             // bin w+16
            const float2 h0 = Hb[w], h1 = Hb[w+16];
            Xlo = cmul(Xlo, mkv(h0.x, h0.y));
            Xhi = cmul(Xhi, mkv(h1.x, h1.y));
            d[2*w]   = Xlo + Xhi;                          // A_w
            d[2*w+1] = mri(Xlo - Xhi, CT[w], ST[w]);       // B_w = (Xlo-Xhi)*conj(W32^w)
        }
        dft16<true,false,2>(d);        // y[2i]   at d[2i]
        dft16<true,false,2>(d+1);      // y[2i+1] at d[2i+1]
        uint4* __restrict__ dstv = reinterpret_cast<uint4*>(buf + BSTR*t);
#pragma unroll
        for (int k=0;k<8;++k){
            uint4 v;
            v.x = f2h(d[4*k+0]); v.y = f2h(d[4*k+1]);
            v.z = f2h(d[4*k+2]); v.w = f2h(d[4*k+3]);
            dstv[k] = v;
        }
    }
    __syncthreads();

    // ---- Pass B': inverse radix-16, stride 32 (positive-angle twiddles) ----
    {
        const int j2 = t & 31;
        const int a0 = 576*(t>>5) + j2;
        const int a1 = a0 + 4608;
#pragma unroll
        for (int q=0;q<16;++q){
            d[q]    = ldh(buf, a0 + BSTR*q);
            d[16+q] = ldh(buf, a1 + BSTR*q);
        }
        float sn, cs; __sincosf(TWO_PI * (float)j2 / 512.f, &sn, &cs);
        tw_apply2(d, mkv(cs, sn));
        dft16<true,false,1>(d);
        dft16<true,false,1>(d+16);
#pragma unroll
        for (int m=0;m<16;++m){
            sth(buf, a0 + BSTR*m, d[m]);
            sth(buf, a1 + BSTR*m, d[16+m]);
        }
    }
    __syncthreads();

    // ---- Pass A': inverse radix-16, stride 512; direct overlap-add ----
    {
#pragma unroll
        for (int q=0;q<16;++q){
            d[q]    = ldh(buf, pa0       + 576*q);
            d[16+q] = ldh(buf, pa0 + 288 + 576*q);
        }
        float sn, cs; __sincosf(TWO_PI * (float)t / 8192.f, &sn, &cs);
        const vf2 w0 = mkv(cs, sn);
        tw_apply(d,    w0);
        tw_apply(d+16, cmul(w0, mkv(0.980785280403230f, 0.195090322016128f))); // * e^{+i pi/16}
        dft16<true,false,1>(d);
        dft16<true,false,1>(d+16);
        // d[16h+m] = y[time (t+256h) + 512m]; Re -> block a, Im -> block b.
        float* ob = out + (size_t)b*SEQ;
        const int pa = 2*pr*BS;
        const bool last = (pr == NPAIR-1);
#pragma unroll
        for (int h=0; h<2; ++h){
            const int j = t + 256*h;
#pragma unroll
            for (int mm=0;mm<8;++mm){
                const int klo = j + 512*mm;                      // 0..4095
                const vf2 ylo = d[16*h + mm];
                const vf2 yhi = d[16*h + mm + 8];
                atomicAdd(&ob[pa+klo], ylo.x);                   // even span (2 writers)
                ob[pa+BS+klo] = yhi.x + ylo.y;                   // odd span (sole writer)
                if (!last) atomicAdd(&ob[pa+2*BS+klo], yhi.y);   // even span (2 writers)
            }
        }
    }
}

// ---------------------------------------------------------------------------
extern "C" void kernel_launch(void* const* d_in, const int* in_sizes, int n_in,
                              void* d_out, int out_size, void* d_ws, size_t ws_size,
                              hipStream_t stream) {
    const float* x   = (const float*)d_in[0];
    const float* c   = (const float*)d_in[1];
    const float* Wf  = (const float*)d_in[2];
    const float* bfv = (const float*)d_in[3];
    const float* Wp  = (const float*)d_in[4];
    const float* bpv = (const float*)d_in[5];

    float*  out = (float*)d_out;
    float2* H   = (float2*)d_ws;                      // BATCH*FL*8B = 2 MiB

    // h_kernel also zeroes the even output spans (odd spans are plain-stored).
    h_kernel<<<dim3(FL/2/256, BATCH), 256, 0, stream>>>(c, Wf, bfv, Wp, bpv, H,
                                                        (float4*)d_out);
    fft_kernel<<<dim3(NPAIR, BATCH), 256, LDSN*sizeof(__half2), stream>>>(x, H, out);
}